// Round 3
// baseline (427.842 us; speedup 1.0000x reference)
//
#include <hip/hip_runtime.h>

#define NEG_INF (-1e9f)
#define SCALE_F 0.08838834764831845f

typedef __attribute__((ext_vector_type(8))) short short8;
typedef __attribute__((ext_vector_type(4))) float float4v;

__device__ __constant__ int cDR[8] = {1,1,0,-1,-1,-1,0,1};
__device__ __constant__ int cDC[8] = {0,1,1,1,0,-1,-1,-1};
__device__ __constant__ int cKR[8] = {2,1,-1,-2,-2,-1,1,2};
__device__ __constant__ int cKC[8] = {1,2,2,1,-1,-2,-2,-1};

__device__ __forceinline__ ushort f2bf(float f) {
  union { float f; unsigned u; } a; a.f = f;
  unsigned u = a.u;
  return (ushort)((u + 0x7FFFu + ((u >> 16) & 1u)) >> 16);
}

// async 16B/lane copy global -> LDS: lane i's 16B lands at ldsbase + i*16.
__device__ __forceinline__ void glds16(const void* g, void* l) {
  __builtin_amdgcn_global_load_lds(
      (const __attribute__((address_space(1))) unsigned int*)g,
      (__attribute__((address_space(3))) unsigned int*)l, 16, 0, 0);
}

// truncation-pack 8 f32 -> 8 bf16
__device__ __forceinline__ short8 pack8(float4 a, float4 b) {
  union { short8 v; unsigned u[4]; } o;
  o.u[0] = (__float_as_uint(a.y) & 0xFFFF0000u) | (__float_as_uint(a.x) >> 16);
  o.u[1] = (__float_as_uint(a.w) & 0xFFFF0000u) | (__float_as_uint(a.z) >> 16);
  o.u[2] = (__float_as_uint(b.y) & 0xFFFF0000u) | (__float_as_uint(b.x) >> 16);
  o.u[3] = (__float_as_uint(b.w) & 0xFFFF0000u) | (__float_as_uint(b.z) >> 16);
  return o.v;
}

// Wsw: BK=32 chunk-major [kc][row][sg*8+j] bf16, 9216 elems (18432 B)/chunk.
// rows 0..287: 0-127 Wq cols, 128-255 Wk cols, 256-264 Wu cols, 265-287 zero.
// XOR swizzle on 16B granules: position sg holds source granule sg^(row&3).
__global__ void wconv_kernel(const float* __restrict__ Wq,
                             const float* __restrict__ Wk,
                             const float* __restrict__ Wu,
                             ushort* __restrict__ Wsw) {
  int row = blockIdx.x;  // 0..287
  for (int k = threadIdx.x; k < 1024; k += 256) {
    float v;
    if (row < 128)      v = Wq[k * 128 + row];
    else if (row < 256) v = Wk[k * 128 + (row - 128)];
    else if (row < 265) v = Wu[k * 9 + (row - 256)];
    else                v = 0.f;
    int kc = k >> 5, kin = k & 31, g = kin >> 3, j = kin & 7;
    int sg = g ^ (row & 3);
    Wsw[(size_t)kc * 9216 + row * 32 + sg * 8 + j] = f2bf(v);
  }
}

// K1: q/k projection GEMM. M=2 batches x 64 rows = 128, N=256 (+promo), K=1024.
// Grid B/2 blocks, 256 threads (2x2 waves, wave tile 64x128).
// Writes q,k bf16 to qkbuf[batch][{q,k}][64][128] with 16B-granule XOR swizzle
// (key row&7) so attn_gather's fragment reads are conflict-free.
__global__ __launch_bounds__(256, 2)
void qk_gemm(const float* __restrict__ x,
             const float* __restrict__ bq,
             const float* __restrict__ bk,
             const float* __restrict__ bu,
             const ushort* __restrict__ Wsw,
             ushort* __restrict__ qkbuf,
             float* __restrict__ out) {
  __shared__ __align__(16) char smem[34816];
  char* xsB = smem;           // f32 [128 rows][128 B], swizzled granules
  char* wtB = smem + 16384;   // bf16 [288 rows][64 B], pre-swizzled

  const int tid = threadIdx.x;
  const int w = tid >> 6, lane = tid & 63;
  const int l15 = lane & 15, qd = lane >> 4;
  const int wm = w >> 1, wn = w & 1;

  const char* xb = (const char*)x + (size_t)blockIdx.x * 524288;  // 128 rows
  const char* WsB = (const char*)Wsw + (size_t)lane * 16;

  // x staging: 16 KB/chunk = 16 segs of 1KB (8 rows); 4 calls/wave.
  int xsrc[4];
  #pragma unroll
  for (int c = 0; c < 4; ++c) {
    int s = c * 4 + w;
    int row = s * 8 + (lane >> 3);
    int sg = lane & 7;
    xsrc[c] = row * 4096 + ((sg ^ (row & 7)) * 16);
  }

  float4v acc[4][8];
  #pragma unroll
  for (int i = 0; i < 4; ++i)
    #pragma unroll
    for (int j = 0; j < 8; ++j)
      acc[i][j] = (float4v){0.f, 0.f, 0.f, 0.f};
  float4v aup = (float4v){0.f, 0.f, 0.f, 0.f};

  #pragma unroll 1
  for (int kc = 0; kc < 32; ++kc) {
    #pragma unroll
    for (int c = 0; c < 4; ++c)
      glds16(xb + kc * 128 + xsrc[c], xsB + (c * 4 + w) * 1024);
    const char* wsrc = WsB + (size_t)kc * 18432;
    #pragma unroll
    for (int c = 0; c < 5; ++c) {
      int s = c * 4 + w;
      if (s < 18) glds16(wsrc + s * 1024, wtB + s * 1024);
    }
    __syncthreads();

    short8 af[4];
    #pragma unroll
    for (int mt = 0; mt < 4; ++mt) {
      int row = wm * 64 + mt * 16 + l15;
      int g0 = qd * 2;
      float4 v0 = *(const float4*)(xsB + row * 128 + ((g0 ^ (row & 7)) * 16));
      float4 v1 = *(const float4*)(xsB + row * 128 + (((g0 + 1) ^ (row & 7)) * 16));
      af[mt] = pack8(v0, v1);
    }
    const int gb = (qd ^ (l15 & 3)) * 16;
    short8 bf[8];
    #pragma unroll
    for (int nt = 0; nt < 8; ++nt) {
      int rowB = wn * 128 + nt * 16 + l15;
      bf[nt] = *(const short8*)(wtB + rowB * 64 + gb);
    }
    #pragma unroll
    for (int mt = 0; mt < 4; ++mt)
      #pragma unroll
      for (int nt = 0; nt < 8; ++nt)
        acc[mt][nt] = __builtin_amdgcn_mfma_f32_16x16x32_bf16(
            af[mt], bf[nt], acc[mt][nt], 0, 0, 0);
    if (wn) {
      short8 ub = *(const short8*)(wtB + (256 + l15) * 64 + gb);
      aup = __builtin_amdgcn_mfma_f32_16x16x32_bf16(af[3], ub, aup, 0, 0, 0);
    }
    __syncthreads();
  }

  const int batch = blockIdx.x * 2 + wm;

  // promo: wn waves, C rows 48..55 via mt=3 tile (qd<2), cols l15<9
  if (wn && qd < 2 && l15 < 9) {
    float bias = bu[l15];
    #pragma unroll
    for (int r = 0; r < 4; ++r) {
      int f = 48 + qd * 4 + r;
      out[(size_t)batch * 4672 + f * 73 + 64 + l15] = aup[r] + bias;
    }
  }

  // epilogue: q (wn=0, scaled) / k (wn=1) -> qkbuf, swizzled bf16
  {
    const float* bias_ptr = wn ? bk : bq;
    ushort* dst = qkbuf + (size_t)batch * 16384 + wn * 8192;
    #pragma unroll
    for (int nt = 0; nt < 8; ++nt) {
      int p = nt * 16 + l15;
      float bias = bias_ptr[p];
      int g = p >> 3, j = p & 7;
      #pragma unroll
      for (int mt = 0; mt < 4; ++mt)
        #pragma unroll
        for (int r = 0; r < 4; ++r) {
          int f = mt * 16 + qd * 4 + r;
          float v = acc[mt][nt][r] + bias;
          if (!wn) v *= SCALE_F;
          dst[f * 128 + ((g ^ (f & 7)) * 8) + j] = f2bf(v);
        }
    }
  }
}

// K2: per batch: S = q' k'^T (64x64), plane gather + masks, store 64x73.
__global__ __launch_bounds__(256)
void attn_gather(const ushort* __restrict__ qkbuf,
                 float* __restrict__ out) {
  __shared__ __align__(16) char smem[32768];  // q [64][256B] | k [64][256B]
  float* Sl = (float*)smem;                   // overlays after frag reads

  const int tid = threadIdx.x;
  const int w = tid >> 6, lane = tid & 63;
  const int l15 = lane & 15, qd = lane >> 4;

  const char* src = (const char*)qkbuf + (size_t)blockIdx.x * 32768 +
                    (size_t)lane * 16;
  #pragma unroll
  for (int c = 0; c < 8; ++c)
    glds16(src + (c * 4 + w) * 1024, smem + (c * 4 + w) * 1024);
  __syncthreads();

  float4v acc2[4];
  #pragma unroll
  for (int nt = 0; nt < 4; ++nt) acc2[nt] = (float4v){0.f, 0.f, 0.f, 0.f};
  #pragma unroll
  for (int kp = 0; kp < 4; ++kp) {
    int m = w * 16 + l15;
    short8 a2 = *(const short8*)(smem + m * 256 + (((kp * 4 + qd) ^ (m & 7)) * 16));
    #pragma unroll
    for (int nt = 0; nt < 4; ++nt) {
      int t = nt * 16 + l15;
      short8 b2 = *(const short8*)(smem + 16384 + t * 256 +
                                   (((kp * 4 + qd) ^ (t & 7)) * 16));
      acc2[nt] = __builtin_amdgcn_mfma_f32_16x16x32_bf16(a2, b2, acc2[nt], 0, 0, 0);
    }
  }
  __syncthreads();
  #pragma unroll
  for (int nt = 0; nt < 4; ++nt)
    #pragma unroll
    for (int r = 0; r < 4; ++r)
      Sl[(w * 16 + qd * 4 + r) * 65 + nt * 16 + l15] = acc2[nt][r];
  __syncthreads();

  float* outb = out + (size_t)blockIdx.x * 4672;
  for (int idx = tid; idx < 4672; idx += 256) {
    int f = idx / 73;
    int j = idx - f * 73;
    float val;
    if (j < 64) {
      int rr = f >> 3, cc = f & 7;
      int nr, nc;
      if (j < 56) {
        int d = j / 7;
        int dist = j - d * 7 + 1;
        nr = rr + cDR[d] * dist;
        nc = cc + cDC[d] * dist;
      } else {
        nr = rr + cKR[j - 56];
        nc = cc + cKC[j - 56];
      }
      val = (nr >= 0 && nr < 8 && nc >= 0 && nc < 8) ? Sl[f * 65 + nr * 8 + nc]
                                                     : NEG_INF;
    } else {
      if (f >= 48 && f < 56) continue;  // promo rows written by qk_gemm
      val = NEG_INF;
    }
    outb[idx] = val;
  }
}

extern "C" void kernel_launch(void* const* d_in, const int* in_sizes, int n_in,
                              void* d_out, int out_size, void* d_ws, size_t ws_size,
                              hipStream_t stream) {
  const float* x  = (const float*)d_in[0];
  const float* Wq = (const float*)d_in[1];
  const float* bq = (const float*)d_in[2];
  const float* Wk = (const float*)d_in[3];
  const float* bk = (const float*)d_in[4];
  const float* Wu = (const float*)d_in[5];
  const float* bu = (const float*)d_in[6];
  float* out = (float*)d_out;
  ushort* Wsw   = (ushort*)d_ws;                       // 576 KB
  ushort* qkbuf = (ushort*)((char*)d_ws + (1 << 20));  // 32 MB

  const int B = in_sizes[0] / 65536;

  wconv_kernel<<<288, 256, 0, stream>>>(Wq, Wk, Wu, Wsw);
  qk_gemm<<<B / 2, 256, 0, stream>>>(x, bq, bk, bu, Wsw, qkbuf, out);
  attn_gather<<<B, 256, 0, stream>>>(qkbuf, out);
}

// Round 4
// 422.344 us; speedup vs baseline: 1.0130x; 1.0130x over previous
//
#include <hip/hip_runtime.h>

#define NEG_INF (-1e9f)
#define SCALE_F 0.08838834764831845f

typedef __attribute__((ext_vector_type(8))) short short8;
typedef __attribute__((ext_vector_type(4))) float float4v;

__device__ __constant__ int cDR[8] = {1,1,0,-1,-1,-1,0,1};
__device__ __constant__ int cDC[8] = {0,1,1,1,0,-1,-1,-1};
__device__ __constant__ int cKR[8] = {2,1,-1,-2,-2,-1,1,2};
__device__ __constant__ int cKC[8] = {1,2,2,1,-1,-2,-2,-1};

__device__ __forceinline__ ushort f2bf(float f) {
  union { float f; unsigned u; } a; a.f = f;
  unsigned u = a.u;
  return (ushort)((u + 0x7FFFu + ((u >> 16) & 1u)) >> 16);
}

// async 16B/lane copy global -> LDS: lane i's 16B lands at ldsbase + i*16.
__device__ __forceinline__ void glds16(const void* g, void* l) {
  __builtin_amdgcn_global_load_lds(
      (const __attribute__((address_space(1))) unsigned int*)g,
      (__attribute__((address_space(3))) unsigned int*)l, 16, 0, 0);
}

// truncation-pack 8 f32 -> 8 bf16
__device__ __forceinline__ short8 pack8(float4 a, float4 b) {
  union { short8 v; unsigned u[4]; } o;
  o.u[0] = (__float_as_uint(a.y) & 0xFFFF0000u) | (__float_as_uint(a.x) >> 16);
  o.u[1] = (__float_as_uint(a.w) & 0xFFFF0000u) | (__float_as_uint(a.z) >> 16);
  o.u[2] = (__float_as_uint(b.y) & 0xFFFF0000u) | (__float_as_uint(b.x) >> 16);
  o.u[3] = (__float_as_uint(b.w) & 0xFFFF0000u) | (__float_as_uint(b.z) >> 16);
  return o.v;
}

// unaligned-16 LDS load as 2x8B (for stride-132 padded buffers)
__device__ __forceinline__ short8 lds_load8(const ushort* p) {
  union { short8 v; ushort4 h[2]; } u;
  u.h[0] = *(const ushort4*)(p);
  u.h[1] = *(const ushort4*)(p + 4);
  return u.v;
}

// Wsw: BK=32 chunk-major [kc][row][sg*8+j] bf16, 9216 elems (18432 B)/chunk.
// rows 0..287: 0-127 Wq cols, 128-255 Wk cols, 256-264 Wu cols, 265-287 zero.
// XOR swizzle on 16B granules: position sg holds source granule sg^(row&3).
__global__ void wconv_kernel(const float* __restrict__ Wq,
                             const float* __restrict__ Wk,
                             const float* __restrict__ Wu,
                             ushort* __restrict__ Wsw) {
  int row = blockIdx.x;  // 0..287
  for (int k = threadIdx.x; k < 1024; k += 256) {
    float v;
    if (row < 128)      v = Wq[k * 128 + row];
    else if (row < 256) v = Wk[k * 128 + (row - 128)];
    else if (row < 265) v = Wu[k * 9 + (row - 256)];
    else                v = 0.f;
    int kc = k >> 5, kin = k & 31, g = kin >> 3, j = kin & 7;
    int sg = g ^ (row & 3);
    Wsw[(size_t)kc * 9216 + row * 32 + sg * 8 + j] = f2bf(v);
  }
}

// Fused: projection GEMM (M=128 = 2 batches, N=256+promo, K=1024, BK=32,
// software-pipelined glds staging with raw barriers + vmcnt(4)), then per-batch
// S = q k^T, plane gather, store.
__global__ __launch_bounds__(256, 2)
void apol_fused(const float* __restrict__ x,
                const float* __restrict__ bq,
                const float* __restrict__ bk,
                const float* __restrict__ bu,
                const ushort* __restrict__ Wsw,
                float* __restrict__ out) {
  // phase1: xb0 f32[128][128B] | xb1 same | wt bf16[272][64B]  = 50176 B
  // phase2: qs[64][132] bf16 | ks[64][132] bf16 | Sl f32[64][65] (overlay qs)
  __shared__ __align__(16) char smem[50176];
  char*   xb0 = smem;
  char*   xb1 = smem + 16384;
  char*   wtB = smem + 32768;
  ushort* qs  = (ushort*)smem;
  ushort* ks  = (ushort*)(smem + 16896);
  float*  Sl  = (float*)smem;

  const int tid = threadIdx.x;
  const int w = tid >> 6, lane = tid & 63;
  const int l15 = lane & 15, qd = lane >> 4;
  const int wm = w >> 1, wn = w & 1;

  const char* xg = (const char*)x + (size_t)blockIdx.x * 524288;  // 128 rows
  const char* wg = (const char*)Wsw + (size_t)lane * 16;

  // x staging: 16 segs of 1KB (8 rows x 8 granules); wave w: segs {4c+w}.
  int xsrc[4];
  #pragma unroll
  for (int c = 0; c < 4; ++c) {
    int s = c * 4 + w;
    int row = s * 8 + (lane >> 3);
    int sg = lane & 7;
    xsrc[c] = row * 4096 + ((sg ^ (row & 7)) * 16);
  }

  // fragment LDS offsets (swizzled)
  int aoff[4][2];
  #pragma unroll
  for (int mt = 0; mt < 4; ++mt) {
    int row = wm * 64 + mt * 16 + l15;
    #pragma unroll
    for (int h = 0; h < 2; ++h)
      aoff[mt][h] = row * 128 + (((qd * 2 + h) ^ (row & 7)) * 16);
  }
  const int gb = (qd ^ (l15 & 3)) * 16;
  int boff[8];
  #pragma unroll
  for (int nt = 0; nt < 8; ++nt)
    boff[nt] = (wn * 128 + nt * 16 + l15) * 64 + gb;
  const int uoff = (256 + l15) * 64 + gb;

  float4v acc[4][8];
  #pragma unroll
  for (int i = 0; i < 4; ++i)
    #pragma unroll
    for (int j = 0; j < 8; ++j)
      acc[i][j] = (float4v){0.f, 0.f, 0.f, 0.f};
  float4v aup = (float4v){0.f, 0.f, 0.f, 0.f};

  // ---- preamble: W(0), x(0), x(1) (newest 4 vm ops = x(1)) ----
  {
    const char* s0 = wg;
    #pragma unroll
    for (int c = 0; c < 5; ++c) {
      int sg = c * 4 + w;
      if (sg < 17) glds16(s0 + sg * 1024, wtB + sg * 1024);
    }
    #pragma unroll
    for (int c = 0; c < 4; ++c)
      glds16(xg + xsrc[c], xb0 + (c * 4 + w) * 1024);
    #pragma unroll
    for (int c = 0; c < 4; ++c)
      glds16(xg + 128 + xsrc[c], xb1 + (c * 4 + w) * 1024);
  }

  // ---- pipelined K loop: never vmcnt(0) until the last chunk ----
  #pragma unroll 1
  for (int kc = 0; kc < 32; ++kc) {
    if (kc == 31) asm volatile("s_waitcnt vmcnt(0)" ::: "memory");
    else          asm volatile("s_waitcnt vmcnt(4)" ::: "memory");
    __builtin_amdgcn_s_barrier();
    asm volatile("" ::: "memory");

    const char* xsB = (kc & 1) ? xb1 : xb0;
    short8 af[4];
    #pragma unroll
    for (int mt = 0; mt < 4; ++mt) {
      float4 v0 = *(const float4*)(xsB + aoff[mt][0]);
      float4 v1 = *(const float4*)(xsB + aoff[mt][1]);
      af[mt] = pack8(v0, v1);
    }
    short8 bf[8];
    #pragma unroll
    for (int nt = 0; nt < 8; ++nt)
      bf[nt] = *(const short8*)(wtB + boff[nt]);
    #pragma unroll
    for (int mt = 0; mt < 4; ++mt)
      #pragma unroll
      for (int nt = 0; nt < 8; ++nt)
        acc[mt][nt] = __builtin_amdgcn_mfma_f32_16x16x32_bf16(
            af[mt], bf[nt], acc[mt][nt], 0, 0, 0);
    if (wn) {
      short8 ub = *(const short8*)(wtB + uoff);
      aup = __builtin_amdgcn_mfma_f32_16x16x32_bf16(af[3], ub, aup, 0, 0, 0);
    }

    asm volatile("" ::: "memory");
    __builtin_amdgcn_s_barrier();

    if (kc < 31) {  // W(kc+1) first, then x(kc+2): newest 4 stay = x
      const char* s1 = wg + (size_t)(kc + 1) * 18432;
      #pragma unroll
      for (int c = 0; c < 5; ++c) {
        int sg = c * 4 + w;
        if (sg < 17) glds16(s1 + sg * 1024, wtB + sg * 1024);
      }
    }
    if (kc < 30) {
      char* dst = (kc & 1) ? xb1 : xb0;  // buffer just freed by compute(kc)
      #pragma unroll
      for (int c = 0; c < 4; ++c)
        glds16(xg + (kc + 2) * 128 + xsrc[c], dst + (c * 4 + w) * 1024);
    }
  }

  // ---- promo rows: wn waves hold x-rows 48..63 of batch wm in aup ----
  if (wn && qd < 2 && l15 < 9) {
    float bias = bu[l15];
    #pragma unroll
    for (int r = 0; r < 4; ++r) {
      int f = 48 + qd * 4 + r;
      out[(size_t)(blockIdx.x * 2 + wm) * 4672 + f * 73 + 64 + l15] =
          aup[r] + bias;
    }
  }

  // ---- per-batch: epilogue -> qs/ks, S = q k^T, gather, store ----
  #pragma unroll 1
  for (int bi = 0; bi < 2; ++bi) {
    __syncthreads();
    if (wm == bi) {
      const float* bias_ptr = wn ? bk : bq;
      ushort* dst = wn ? ks : qs;
      #pragma unroll
      for (int nt = 0; nt < 8; ++nt) {
        int p = nt * 16 + l15;
        float bias = bias_ptr[p];
        #pragma unroll
        for (int mt = 0; mt < 4; ++mt)
          #pragma unroll
          for (int r = 0; r < 4; ++r) {
            int row = mt * 16 + qd * 4 + r;
            float v = acc[mt][nt][r] + bias;
            if (!wn) v *= SCALE_F;
            dst[row * 132 + p] = f2bf(v);
          }
      }
    }
    __syncthreads();

    float4v acc2[4];
    #pragma unroll
    for (int nt = 0; nt < 4; ++nt) acc2[nt] = (float4v){0.f, 0.f, 0.f, 0.f};
    #pragma unroll
    for (int kp = 0; kp < 4; ++kp) {
      int kb = kp * 32 + qd * 8;
      short8 a2 = lds_load8(&qs[(w * 16 + l15) * 132 + kb]);
      #pragma unroll
      for (int nt = 0; nt < 4; ++nt) {
        short8 b2 = lds_load8(&ks[(nt * 16 + l15) * 132 + kb]);
        acc2[nt] = __builtin_amdgcn_mfma_f32_16x16x32_bf16(a2, b2, acc2[nt], 0, 0, 0);
      }
    }
    __syncthreads();
    #pragma unroll
    for (int nt = 0; nt < 4; ++nt)
      #pragma unroll
      for (int r = 0; r < 4; ++r)
        Sl[(w * 16 + qd * 4 + r) * 65 + nt * 16 + l15] = acc2[nt][r];
    __syncthreads();

    float* outb = out + (size_t)(blockIdx.x * 2 + bi) * 4672;
    for (int idx = tid; idx < 4672; idx += 256) {
      int f = idx / 73;
      int j = idx - f * 73;
      float val;
      if (j < 64) {
        int rr = f >> 3, cc = f & 7;
        int nr, nc;
        if (j < 56) {
          int d = j / 7;
          int dist = j - d * 7 + 1;
          nr = rr + cDR[d] * dist;
          nc = cc + cDC[d] * dist;
        } else {
          nr = rr + cKR[j - 56];
          nc = cc + cKC[j - 56];
        }
        val = (nr >= 0 && nr < 8 && nc >= 0 && nc < 8) ? Sl[f * 65 + nr * 8 + nc]
                                                       : NEG_INF;
      } else {
        if (f >= 48 && f < 56) continue;  // promo written above
        val = NEG_INF;
      }
      outb[idx] = val;
    }
  }
}

extern "C" void kernel_launch(void* const* d_in, const int* in_sizes, int n_in,
                              void* d_out, int out_size, void* d_ws, size_t ws_size,
                              hipStream_t stream) {
  const float* x  = (const float*)d_in[0];
  const float* Wq = (const float*)d_in[1];
  const float* bq = (const float*)d_in[2];
  const float* Wk = (const float*)d_in[3];
  const float* bk = (const float*)d_in[4];
  const float* Wu = (const float*)d_in[5];
  const float* bu = (const float*)d_in[6];
  float* out = (float*)d_out;
  ushort* Wsw = (ushort*)d_ws;  // 576 KB

  const int B = in_sizes[0] / 65536;

  wconv_kernel<<<288, 256, 0, stream>>>(Wq, Wk, Wu, Wsw);
  apol_fused<<<B / 2, 256, 0, stream>>>(x, bq, bk, bu, Wsw, out);
}

// Round 6
// 416.474 us; speedup vs baseline: 1.0273x; 1.0141x over previous
//
#include <hip/hip_runtime.h>

#define NEG_INF (-1e9f)
#define SCALE_F 0.08838834764831845f

typedef __attribute__((ext_vector_type(8))) short short8;
typedef __attribute__((ext_vector_type(4))) float float4v;

__device__ __constant__ int cDR[8] = {1,1,0,-1,-1,-1,0,1};
__device__ __constant__ int cDC[8] = {0,1,1,1,0,-1,-1,-1};
__device__ __constant__ int cKR[8] = {2,1,-1,-2,-2,-1,1,2};
__device__ __constant__ int cKC[8] = {1,2,2,1,-1,-2,-2,-1};

__device__ __forceinline__ ushort f2bf(float f) {
  union { float f; unsigned u; } a; a.f = f;
  unsigned u = a.u;
  return (ushort)((u + 0x7FFFu + ((u >> 16) & 1u)) >> 16);
}

// async 16B/lane copy global -> LDS: lane i's 16B lands at ldsbase + i*16.
__device__ __forceinline__ void glds16(const void* g, void* l) {
  __builtin_amdgcn_global_load_lds(
      (const __attribute__((address_space(1))) unsigned int*)g,
      (__attribute__((address_space(3))) unsigned int*)l, 16, 0, 0);
}

// truncation-pack 8 f32 -> 8 bf16
__device__ __forceinline__ short8 pack8(float4 a, float4 b) {
  union { short8 v; unsigned u[4]; } o;
  o.u[0] = (__float_as_uint(a.y) & 0xFFFF0000u) | (__float_as_uint(a.x) >> 16);
  o.u[1] = (__float_as_uint(a.w) & 0xFFFF0000u) | (__float_as_uint(a.z) >> 16);
  o.u[2] = (__float_as_uint(b.y) & 0xFFFF0000u) | (__float_as_uint(b.x) >> 16);
  o.u[3] = (__float_as_uint(b.w) & 0xFFFF0000u) | (__float_as_uint(b.z) >> 16);
  return o.v;
}

// Wreg layout: per kc (32 chunks of BK=32), 17 col-blocks (cb) of 16 cols:
// Wreg[kc*8704 + cb*512 + qd*128 + l15*8 + j] = W_col[row=cb*16+l15][k=kc*32+qd*8+j]
// so a wave's B-fragment for (kc,cb) is ONE coalesced 1KB global_load_dwordx4.
// cb 0-7: Wq cols, 8-15: Wk cols, 16: Wu cols 0-8 (rows 265-271 zero).
__global__ void wconv_kernel(const float* __restrict__ Wq,
                             const float* __restrict__ Wk,
                             const float* __restrict__ Wu,
                             ushort* __restrict__ Wreg) {
  int row = blockIdx.x;  // 0..271
  int cb = row >> 4, lr = row & 15;
  for (int k = threadIdx.x; k < 1024; k += 256) {
    float v;
    if (row < 128)      v = Wq[k * 128 + row];
    else if (row < 256) v = Wk[k * 128 + (row - 128)];
    else if (row < 265) v = Wu[k * 9 + (row - 256)];
    else                v = 0.f;
    int kc = k >> 5, kin = k & 31, qd = kin >> 3, j = kin & 7;
    Wreg[kc * 8704 + cb * 512 + qd * 128 + lr * 8 + j] = f2bf(v);
  }
}

// Fused per-batch kernel. M=64, N=256(+9 promo), K=1024, BK=32.
// x: glds double-buffer in DISTINCT __shared__ objects; W: register-streamed
// coalesced global loads (issued BEFORE the glds each iteration so the
// compiler's register wait on W leaves the x-prefetch in flight).
// Top-of-iter wait: vmcnt(7) drains exactly glds(kc) (9 outstanding -> 7);
// last iter (kc=31): 7 outstanding -> vmcnt(5).
__global__ __launch_bounds__(256, 4)
void apol_fused(const float* __restrict__ x,
                const float* __restrict__ bq,
                const float* __restrict__ bk,
                const float* __restrict__ bu,
                const ushort* Wreg,  // not restrict: pinned by asm fences
                float* __restrict__ out) {
  __shared__ __align__(16) char xb0[8192];   // x even chunks / later q rows 0-31
  __shared__ __align__(16) char xb1[8192];   // x odd chunks  / later q rows 32-63
  __shared__ __align__(16) char kbuf[16384]; // later k (64x128 bf16) / Sl f32

  const int tid = threadIdx.x;
  const int w = tid >> 6, lane = tid & 63;
  const int l15 = lane & 15, qd = lane >> 4;

  const char* xg = (const char*)x + (size_t)blockIdx.x * 262144;  // 64x1024 f32
  const char* wgl = (const char*)Wreg + (size_t)lane * 16;

  // x staging: chunk = 64 rows x 128B = 8 segs of 1KB; wave w stages segs w*2+c.
  // XOR-swizzle via source scrambling: LDS slot (row,g) holds src granule
  // g^(row&7).
  int xsrc[2], xdst[2];
  #pragma unroll
  for (int c = 0; c < 2; ++c) {
    int s = w * 2 + c;
    int row = s * 8 + (lane >> 3);
    xsrc[c] = row * 4096 + (((lane & 7) ^ (row & 7)) * 16);
    xdst[c] = s * 1024;
  }

  float4v acc[4][4];
  #pragma unroll
  for (int i = 0; i < 4; ++i)
    #pragma unroll
    for (int j = 0; j < 4; ++j)
      acc[i][j] = (float4v){0.f, 0.f, 0.f, 0.f};
  float4v aup = (float4v){0.f, 0.f, 0.f, 0.f};

  short8 bf[4], ub;

  // ---- preamble: xDMA(0)->xb0, xDMA(1)->xb1, then W(0) ----
  glds16(xg + 0 * 128 + xsrc[0], xb0 + xdst[0]);
  glds16(xg + 0 * 128 + xsrc[1], xb0 + xdst[1]);
  glds16(xg + 1 * 128 + xsrc[0], xb1 + xdst[0]);
  glds16(xg + 1 * 128 + xsrc[1], xb1 + xdst[1]);
  asm volatile("" ::: "memory");
  {
    const char* wp = wgl;  // kc = 0
    #pragma unroll
    for (int nt = 0; nt < 4; ++nt)
      bf[nt] = *(const short8*)(wp + (w * 4 + nt) * 1024);
    ub = *(const short8*)(wp + 16 * 1024);
  }
  asm volatile("" ::: "memory");

  // s_waitcnt simm: lgkmcnt[11:8], expcnt[6:4], vmcnt[3:0] (hi bits 0)
#define KBODY(KC, XBUF)                                                        \
  do {                                                                         \
    if ((KC) == 31) __builtin_amdgcn_s_waitcnt(0xF75); /* vmcnt(5) */          \
    else            __builtin_amdgcn_s_waitcnt(0xF77); /* vmcnt(7) */          \
    __builtin_amdgcn_s_barrier();                                              \
    asm volatile("" ::: "memory");                                             \
    short8 af[4];                                                              \
    _Pragma("unroll") for (int mt = 0; mt < 4; ++mt) {                         \
      int row = mt * 16 + l15;                                                 \
      float4 v0 = *(const float4*)(XBUF + row * 128 +                          \
                                   (((qd * 2) ^ (row & 7)) * 16));             \
      float4 v1 = *(const float4*)(XBUF + row * 128 +                          \
                                   (((qd * 2 + 1) ^ (row & 7)) * 16));         \
      af[mt] = pack8(v0, v1);                                                  \
    }                                                                          \
    _Pragma("unroll") for (int mt = 0; mt < 4; ++mt)                           \
      _Pragma("unroll") for (int nt = 0; nt < 4; ++nt)                         \
          acc[mt][nt] = __builtin_amdgcn_mfma_f32_16x16x32_bf16(               \
              af[mt], bf[nt], acc[mt][nt], 0, 0, 0);                           \
    aup = __builtin_amdgcn_mfma_f32_16x16x32_bf16(af[3], ub, aup, 0, 0, 0);    \
    asm volatile("" ::: "memory");                                             \
    __builtin_amdgcn_s_barrier();                                              \
    if ((KC) < 31) { /* W(kc+1) FIRST: its register wait must not drain x */   \
      const char* wp = wgl + (size_t)((KC) + 1) * 17408;                       \
      _Pragma("unroll") for (int nt = 0; nt < 4; ++nt)                         \
          bf[nt] = *(const short8*)(wp + (w * 4 + nt) * 1024);                 \
      ub = *(const short8*)(wp + 16 * 1024);                                   \
    }                                                                          \
    asm volatile("" ::: "memory");                                             \
    if ((KC) < 30) { /* then x(kc+2) into the buffer compute(kc) just freed */ \
      glds16(xg + ((KC) + 2) * 128 + xsrc[0], XBUF + xdst[0]);                 \
      glds16(xg + ((KC) + 2) * 128 + xsrc[1], XBUF + xdst[1]);                 \
    }                                                                          \
    asm volatile("" ::: "memory");                                             \
  } while (0)

  #pragma unroll 1
  for (int kc2 = 0; kc2 < 16; ++kc2) {
    KBODY(kc2 * 2, xb0);
    KBODY(kc2 * 2 + 1, xb1);
  }
#undef KBODY

  float* outb = out + (size_t)blockIdx.x * 4672;

  // promo rows: every wave's aup is identical (ub = cb16 for all waves);
  // wave 3 writes x-rows 48..55 x Wu cols 0..8.
  if (w == 3 && qd < 2 && l15 < 9) {
    float bias = bu[l15];
    #pragma unroll
    for (int r = 0; r < 4; ++r)
      outb[(48 + qd * 4 + r) * 73 + 64 + l15] = aup[r] + bias;
  }

  __syncthreads();  // K-loop fully done; repurpose LDS

  // epilogue: cols w*64+nt*16+l15. w<2 -> q (scale+bias) into xb0/xb1 (rows
  // 0-31 / 32-63), w>=2 -> k into kbuf (full 64 rows). bf16, stride 128,
  // 16B-granule XOR swizzle (key row&7).
  {
    const bool isq = (w < 2);
    const float* bias_ptr = isq ? bq : bk;
    #pragma unroll
    for (int nt = 0; nt < 4; ++nt) {
      int p = (w & 1) * 64 + nt * 16 + l15;
      float bias = bias_ptr[p];
      int pg = p >> 3, pj = p & 7;
      #pragma unroll
      for (int mt = 0; mt < 4; ++mt)
        #pragma unroll
        for (int r = 0; r < 4; ++r) {
          int row = mt * 16 + qd * 4 + r;
          float v = acc[mt][nt][r] + bias;
          ushort* dst;
          int lrow;
          if (isq) {
            v *= SCALE_F;
            dst = (ushort*)((row & 32) ? xb1 : xb0);
            lrow = row & 31;
          } else {
            dst = (ushort*)kbuf;  // 64 rows x 128 cols = 16384 B exactly
            lrow = row;
          }
          dst[lrow * 128 + ((pg ^ (row & 7)) * 8) + pj] = f2bf(v);
        }
    }
  }
  __syncthreads();

  // GEMM2: S = q k^T (64x64, K=128). Wave w: S rows w*16..+15.
  float4v acc2[4];
  #pragma unroll
  for (int nt = 0; nt < 4; ++nt) acc2[nt] = (float4v){0.f, 0.f, 0.f, 0.f};
  {
    const ushort* qb = (const ushort*)((w & 2) ? xb1 : xb0);
    const ushort* kb = (const ushort*)kbuf;
    int mrow = w * 16 + l15;
    #pragma unroll
    for (int kp = 0; kp < 4; ++kp) {
      int g = kp * 4 + qd;
      short8 a2 = *(const short8*)(qb + (mrow & 31) * 128 +
                                   ((g ^ (mrow & 7)) * 8));
      #pragma unroll
      for (int nt = 0; nt < 4; ++nt) {
        int t = nt * 16 + l15;
        short8 b2 = *(const short8*)(kb + t * 128 + ((g ^ (t & 7)) * 8));
        acc2[nt] = __builtin_amdgcn_mfma_f32_16x16x32_bf16(a2, b2, acc2[nt], 0, 0, 0);
      }
    }
  }
  __syncthreads();  // all q/k reads done; Sl overwrites kbuf

  // Sl: f32 [64][64], granule-swizzled (key row&7)
  float* Slf = (float*)kbuf;
  #pragma unroll
  for (int nt = 0; nt < 4; ++nt)
    #pragma unroll
    for (int r = 0; r < 4; ++r) {
      int row = w * 16 + qd * 4 + r;
      int col = nt * 16 + l15;
      Slf[row * 64 + (((col >> 3) ^ (row & 7)) * 8) + (col & 7)] = acc2[nt][r];
    }
  __syncthreads();

  // gather + masks + store
  for (int idx = tid; idx < 4672; idx += 256) {
    int f = idx / 73;
    int j = idx - f * 73;
    float val;
    if (j < 64) {
      int rr = f >> 3, cc = f & 7;
      int nr, nc;
      if (j < 56) {
        int d = j / 7;
        int dist = j - d * 7 + 1;
        nr = rr + cDR[d] * dist;
        nc = cc + cDC[d] * dist;
      } else {
        nr = rr + cKR[j - 56];
        nc = cc + cKC[j - 56];
      }
      if (nr >= 0 && nr < 8 && nc >= 0 && nc < 8) {
        int t = nr * 8 + nc;
        val = Slf[f * 64 + (((t >> 3) ^ (f & 7)) * 8) + (t & 7)];
      } else {
        val = NEG_INF;
      }
    } else {
      if (f >= 48 && f < 56) continue;  // promo written above
      val = NEG_INF;
    }
    outb[idx] = val;
  }
}

extern "C" void kernel_launch(void* const* d_in, const int* in_sizes, int n_in,
                              void* d_out, int out_size, void* d_ws, size_t ws_size,
                              hipStream_t stream) {
  const float* x  = (const float*)d_in[0];
  const float* Wq = (const float*)d_in[1];
  const float* bq = (const float*)d_in[2];
  const float* Wk = (const float*)d_in[3];
  const float* bk = (const float*)d_in[4];
  const float* Wu = (const float*)d_in[5];
  const float* bu = (const float*)d_in[6];
  float* out = (float*)d_out;
  ushort* Wreg = (ushort*)d_ws;  // 32*8704 ushort = 544 KB

  const int B = in_sizes[0] / 65536;

  wconv_kernel<<<272, 256, 0, stream>>>(Wq, Wk, Wu, Wreg);
  apol_fused<<<B, 256, 0, stream>>>(x, bq, bk, bu, Wreg, out);
}